// Round 3
// baseline (264.611 us; speedup 1.0000x reference)
//
#include <hip/hip_runtime.h>

// Problem constants (fixed by the reference):
//   B=128, L=9, K=3, C_IN=C_OUT=256, P=1680 (perms of [0,0,0,1,1,1,2,2,2], lex order)
#define B_DIM 128
#define L_DIM 9
#define K_DIM 3
#define C 256
#define P_TOT 1680
#define R_DIM 27          // L*K rows of Z per batch
#define CHUNK 210         // p's per stream block (8 chunks per b)
#define LUT_ROWS 39       // 4 pairs x 9 combos + 3 singles (position 8)

// Workspace layout (bytes):
//   [0, 6720)               pkg : u32[P] — five 6-bit LUT row indices per p
//   [16384, 16384+768K)     Wt  : float[3*256*256], Wt[a][c][o] = W[a][o][c]
//   [1M, 1M+3.456M)         Z   : float[128*27*256], Z[b][l*3+a][o]
#define WS_WT_OFF 16384
#define WS_Z_OFF  (1u << 20)

typedef float vfloat4 __attribute__((ext_vector_type(4)));  // for nontemporal stores

__device__ inline float4 add4(float4 a, float4 b) {
    return make_float4(a.x + b.x, a.y + b.y, a.z + b.z, a.w + b.w);
}

// --------------------------------------------------------------- setup ----
// blocks 0..6   : pkg[p] — per position l the type a_l = M1 + 2*M2; pack the
//                 five LUT indices: pair j -> j*9 + a_{2j}*3 + a_{2j+1} (0..35),
//                 single -> 36 + a_8.  Five 6-bit fields in one u32.
// blocks 7..198 : W transpose -> Wt[a][c][o] (z_kernel's W stream coalesced).
__global__ __launch_bounds__(256) void setup_kernel(const float* __restrict__ M,
                                                    const float* __restrict__ W,
                                                    unsigned* __restrict__ pkg,
                                                    float* __restrict__ Wt) {
    int bid = blockIdx.x;
    int t = threadIdx.x;
    if (bid < 7) {
        int p = bid * 256 + t;
        if (p >= P_TOT) return;
        unsigned a[L_DIM];
#pragma unroll
        for (int l = 0; l < L_DIM; ++l) {
            float m1 = M[(1 * P_TOT + p) * L_DIM + l];
            float m2 = M[(2 * P_TOT + p) * L_DIM + l];
            a[l] = (unsigned)(m1 + 2.0f * m2 + 0.5f);
        }
        unsigned w = 0;
#pragma unroll
        for (int j = 0; j < 4; ++j)
            w |= (unsigned)(j * 9 + a[2 * j] * 3 + a[2 * j + 1]) << (6 * j);
        w |= (36u + a[8]) << 24;
        pkg[p] = w;
    } else {
        int tb = bid - 7;  // 0..191, each does 4 (a,c) rows of 256 o's
#pragma unroll
        for (int i = 0; i < 4; ++i) {
            int rowid = tb * 4 + i;          // 0..767
            int aa = rowid >> 8;
            int c = rowid & 255;
            Wt[(aa * C + c) * C + t] = W[(aa * C + t) * C + c];
        }
    }
}

// ------------------------------------------------------------------- Z ----
// Z[b][l*3+a][o] = sum_c x[b,l,c] * Wt[a][c][o], once per b.
// 256 blocks = (b, o-half) x 384 threads = (a 0..2, o' 0..127); no LDS:
//   - w loads lane-coalesced from Wt (lanes along o)
//   - x loads wave-uniform -> scalar s_load path.  ~453 MFLOP, a few us.
__global__ __launch_bounds__(384) void z_kernel(const float* __restrict__ x,
                                                const float* __restrict__ Wt,
                                                float* __restrict__ Z) {
    int bid = blockIdx.x;            // 0..255 : (b, o-half)
    int b = bid >> 1;
    int t = threadIdx.x;             // 0..383
    int a = t >> 7;                  // 0..2 (all threads active)
    int o = ((bid & 1) << 7) + (t & 127);

    const float4* __restrict__ xb4 = (const float4*)(x + (size_t)b * (L_DIM * C));
    const float* __restrict__ wp = Wt + (size_t)a * C * C + o;

    float acc[L_DIM];
#pragma unroll
    for (int l = 0; l < L_DIM; ++l) acc[l] = 0.0f;

#pragma unroll 2
    for (int c4 = 0; c4 < C / 4; ++c4) {
        float w0 = wp[(4 * c4 + 0) * C];
        float w1 = wp[(4 * c4 + 1) * C];
        float w2 = wp[(4 * c4 + 2) * C];
        float w3 = wp[(4 * c4 + 3) * C];
#pragma unroll
        for (int l = 0; l < L_DIM; ++l) {
            float4 xv = xb4[l * (C / 4) + c4];   // uniform -> s_load_dwordx4
            acc[l] += xv.x * w0 + xv.y * w1 + xv.z * w2 + xv.w * w3;
        }
    }
#pragma unroll
    for (int l = 0; l < L_DIM; ++l)
        Z[((size_t)b * R_DIM + (l * K_DIM + a)) * C + o] = acc[l];
}

// -------------------------------------------------------------- stream ----
// Floor-seeking version.  Remaining slack removed from the r2 loop:
//   1. pkg words preloaded into ONE VGPR per lane (wave's <=53 p's), fetched
//      per-iter with v_readlane (SGPR-indexed) -> the per-iteration LDS
//      round-trip for pk[] is gone from the critical path entirely.
//   2. 1024 blocks x 256 threads (CHUNK=210): 4 blocks/CU x 39.9 KB LDS =
//      159.7 KB -> exactly fills the CU; 16 waves/CU of store-queue depth.
//   3. unroll 4 -> up to 20 ds_read_b128 + 4 stores in flight per wave.
// Per p: 5 independent ds_read_b128 (pair-sum LUT) + 16 v_add + 1 coalesced
// 1KB/wave nontemporal store.  Per-CU store traffic 860 KB ~ 35 us = the
// binding pipe; LDS pipe ~21 us hides under it.
__global__ __launch_bounds__(256) void stream_kernel(const float* __restrict__ Z,
                                                     const unsigned* __restrict__ pkg,
                                                     float* __restrict__ out) {
    __shared__ float lut[LUT_ROWS * C];   // 39.94 KB

    int bid = blockIdx.x;                 // 0..1023
    int b = bid >> 3;
    int pstart = (bid & 7) * CHUNK;
    int t = threadIdx.x;
    int wave = t >> 6;
    int lane = t & 63;

    int pb = (CHUNK * wave) >> 2;         // 0,52,105,157
    int pe = (CHUNK * (wave + 1)) >> 2;   // 52,105,157,210
    int cnt = pe - pb;                    // 52 or 53 (<= 64)

    // per-lane preload of this wave's packed words (global, L2-hot, 6.7 KB total)
    unsigned vpkg = (lane < cnt) ? pkg[pstart + pb + lane] : 0u;

    // build the pair-sum LUT straight from global Z (L2/L3-hot, 27 KB/b)
    const float4* zg = (const float4*)(Z + (size_t)b * R_DIM * C);
    float4* lutw = (float4*)lut;
#pragma unroll
    for (int it = 0; it < 10; ++it) {     // 10*256 = 2560 >= 39*64 = 2496
        int idx = it * 256 + t;
        if (idx < LUT_ROWS * 64) {
            int r = idx >> 6, q = idx & 63;
            float4 v;
            if (r < 36) {
                int j = r / 9;
                int cmb = r - j * 9;
                int a0 = cmb / 3;
                int a1 = cmb - a0 * 3;
                v = add4(zg[(6 * j + a0) * 64 + q], zg[(6 * j + 3 + a1) * 64 + q]);
            } else {
                v = zg[(24 + r - 36) * 64 + q];
            }
            lutw[idx] = v;
        }
    }
    __syncthreads();

    const float4* lutr = (const float4*)lut;
    vfloat4* out4 = (vfloat4*)out;
    size_t obase = (size_t)(b * P_TOT + pstart + pb);

#pragma unroll 4
    for (int i = 0; i < cnt; ++i) {
        unsigned w = __builtin_amdgcn_readlane(vpkg, i);  // uniform, no mem op
        float4 v0 = lutr[((w)&63u) * 64 + lane];
        float4 v1 = lutr[((w >> 6) & 63u) * 64 + lane];
        float4 v2 = lutr[((w >> 12) & 63u) * 64 + lane];
        float4 v3 = lutr[((w >> 18) & 63u) * 64 + lane];
        float4 v4 = lutr[((w >> 24) & 63u) * 64 + lane];
        float4 s = add4(add4(add4(v0, v1), add4(v2, v3)), v4);
        // coalesced 1KB/wave nontemporal store (write-once streaming output)
        vfloat4 sv = {s.x, s.y, s.z, s.w};
        __builtin_nontemporal_store(sv, &out4[(obase + i) * 64 + lane]);
    }
}

// ------------------------------------------------------------------ launch --
extern "C" void kernel_launch(void* const* d_in, const int* in_sizes, int n_in,
                              void* d_out, int out_size, void* d_ws, size_t ws_size,
                              hipStream_t stream) {
    const float* x = (const float*)d_in[0];  // (128, 9, 256)
    const float* W = (const float*)d_in[1];  // (3, 256, 256)
    const float* M = (const float*)d_in[2];  // (3, 1680, 9)
    float* out = (float*)d_out;              // (128, 1680, 256)

    unsigned* pkg = (unsigned*)d_ws;
    float* Wt = (float*)((char*)d_ws + WS_WT_OFF);
    float* Z = (float*)((char*)d_ws + WS_Z_OFF);

    setup_kernel<<<199, 256, 0, stream>>>(M, W, pkg, Wt);
    z_kernel<<<256, 384, 0, stream>>>(x, Wt, Z);
    stream_kernel<<<1024, 256, 0, stream>>>(Z, pkg, out);
}